// Round 6
// baseline (100.122 us; speedup 1.0000x reference)
//
#include <hip/hip_runtime.h>

#define IN_FEATURES 4096
#define OUT_FEATURES 11008
#define KO 128            // k-tiles per partition (2048/16)
#define NW 32             // int32 words per trellis block
#define SEG 32            // split-k segments per partition
#define KO_PER_SEG (KO / SEG)   // 4
#define NPART (SEG * 2)         // 64 partial sums per output element

// R6: minimal per-thread dependency chain.
//  - wave lanes double as [batch(4) x k(16)] for x: ONE coalesced load per
//    k-tile, values pulled into scalar operands via v_readlane (const lane).
//  - trellis odd word via shfl_up (lane-1 holds word 2tx-1): ONE int2 load.
//  - explicit next-iter prefetch; tiny transient live set; no launch_bounds
//    pressure, no unroll pragma on k-loop.
__device__ __forceinline__ float rl(float v, int l) {
    return __builtin_bit_cast(float,
        __builtin_amdgcn_readlane(__builtin_bit_cast(int, v), l));
}

__global__ __launch_bounds__(256) void tcq_decode_kernel(
    const float* __restrict__ inp,       // [4][4096]
    const int* __restrict__ trellis1,    // [688*128][32]
    const int* __restrict__ trellis2,
    const float* __restrict__ tlut,      // [512][2]
    float* __restrict__ ws)              // [NPART][4][11008]
{
    __shared__ float lut[1024];          // 4 KB, only LDS use
    ((float4*)lut)[threadIdx.x] = ((const float4*)tlut)[threadIdx.x];

    const int tid  = threadIdx.x;
    const int lane = tid & 63;
    const int wid  = tid >> 6;
    const int tx   = lane & 15;          // row within 16x16 tile
    const int mt   = lane >> 4;          // m-tile within wave (trellis role)
    const int mo   = blockIdx.x * 16 + wid * 4 + mt;
    const int m    = mo * 16 + tx;
    const int seg  = blockIdx.y;
    const int part = blockIdx.z;
    const int ko0  = seg * KO_PER_SEG;

    const int* __restrict__ tre =
        (part ? trellis2 : trellis1) + (mo * KO + ko0) * NW;
    // x role of the same lanes: batch = lane>>4, k_local = lane&15
    const float* __restrict__ xp =
        inp + (lane >> 4) * IN_FEATURES + part * 2048 + ko0 * 16 + (lane & 15);

    float accE[4] = {0.f, 0.f, 0.f, 0.f};
    float accO[4] = {0.f, 0.f, 0.f, 0.f};

    // prefetch iteration 0
    float xv = xp[0];
    int2  wp = *reinterpret_cast<const int2*>(tre + 2 * tx);

    __syncthreads();

    for (int kk = 0; kk < KO_PER_SEG; ++kk) {
        float xv_n = 0.f; int2 wp_n = {0, 0};
        if (kk + 1 < KO_PER_SEG) {
            xv_n = xp[(kk + 1) * 16];
            wp_n = *reinterpret_cast<const int2*>(tre + (kk + 1) * NW + 2 * tx);
        }

        int wm1 = __shfl_up(wp.y, 1);        // lane-1's wp.y == word 2tx-1
        if (tx == 0) wm1 = 0;                // trellis state starts at 0
        const unsigned comb0 = (unsigned(wm1)  << 16) | (unsigned(wp.x) & 0xFFFFu);
        const unsigned comb1 = (unsigned(wp.x) << 16) | (unsigned(wp.y) & 0xFFFFu);

        #pragma unroll
        for (int j = 0; j < 8; ++j) {
            const unsigned comb  = (j < 4) ? comb0 : comb1;
            const int      shift = 12 - 4 * (j & 3);
            const unsigned idx   = (comb >> shift) & 0x1FFu;
            float2 w = *reinterpret_cast<const float2*>(&lut[idx * 2]);  // gather
            #pragma unroll
            for (int b = 0; b < 4; ++b) {
                accE[b] = fmaf(w.x, rl(xv, b * 16 + 2 * j),     accE[b]);
                accO[b] = fmaf(w.y, rl(xv, b * 16 + 2 * j + 1), accO[b]);
            }
        }
        xv = xv_n; wp = wp_n;
    }

    float* wsp = ws + (size_t)(part * SEG + seg) * 4 * OUT_FEATURES;
    #pragma unroll
    for (int b = 0; b < 4; ++b)
        wsp[b * OUT_FEATURES + m] = accE[b] + accO[b];   // 64-contiguous stores
}

__global__ __launch_bounds__(256) void tcq_reduce_kernel(
    const float* __restrict__ ws,        // [NPART][4*11008]
    float* __restrict__ out)             // [4*11008]
{
    const int i = blockIdx.x * 256 + threadIdx.x;
    if (i < 4 * OUT_FEATURES) {
        float s = 0.f;
        #pragma unroll
        for (int p = 0; p < NPART; ++p)
            s += ws[(size_t)p * 4 * OUT_FEATURES + i];
        out[i] = s;
    }
}

extern "C" void kernel_launch(void* const* d_in, const int* in_sizes, int n_in,
                              void* d_out, int out_size, void* d_ws, size_t ws_size,
                              hipStream_t stream) {
    const float* inp  = (const float*)d_in[0];
    const int*   t1   = (const int*)d_in[1];
    const int*   t2   = (const int*)d_in[2];
    const float* tlut = (const float*)d_in[3];
    float* out = (float*)d_out;
    float* ws  = (float*)d_ws;   // NPART*4*11008*4 B = 11.3 MB

    dim3 grid1(43, SEG, 2);      // 2752 blocks
    hipLaunchKernelGGL(tcq_decode_kernel, grid1, dim3(256), 0, stream,
                       inp, t1, t2, tlut, ws);

    dim3 grid2((4 * OUT_FEATURES + 255) / 256);   // 172 blocks
    hipLaunchKernelGGL(tcq_reduce_kernel, grid2, dim3(256), 0, stream,
                       ws, out);
}